// Round 13
// baseline (353.630 us; speedup 1.0000x reference)
//
#include <hip/hip_runtime.h>
#include <hip/hip_bf16.h>

#define DEVINL __device__ __forceinline__

typedef __bf16 bf16x8 __attribute__((ext_vector_type(8)));
typedef float f32x4 __attribute__((ext_vector_type(4)));
typedef unsigned short u16x8 __attribute__((ext_vector_type(8)));
typedef unsigned short u16x4 __attribute__((ext_vector_type(4)));

DEVINL unsigned short f2bf(float f) {
  __hip_bfloat16 h = __float2bfloat16(f);
  return __builtin_bit_cast(unsigned short, h);
}

DEVINL float bf2f(unsigned short u) {
  return __builtin_bit_cast(float, ((unsigned)u) << 16);
}

DEVINL f32x4 mfma16(bf16x8 a, bf16x8 b, f32x4 c) {
  return __builtin_amdgcn_mfma_f32_16x16x32_bf16(a, b, c, 0, 0, 0);
}

DEVINL void gload_lds16(const void* g, void* l) {
  __builtin_amdgcn_global_load_lds(
      (const __attribute__((address_space(1))) unsigned int*)g,
      (__attribute__((address_space(3))) unsigned int*)l, 16, 0, 0);
}

// ---------- P0: x f32 -> bf16 ----------
__global__ __launch_bounds__(256) void k_cvt(const float* __restrict__ x,
                                             u16x8* __restrict__ xb) {
  int i = blockIdx.x * 256 + threadIdx.x;
  const float* p = x + (size_t)i * 8;
  float4 a = *(const float4*)p;
  float4 b = *(const float4*)(p + 4);
  u16x8 o;
  o[0] = f2bf(a.x); o[1] = f2bf(a.y); o[2] = f2bf(a.z); o[3] = f2bf(a.w);
  o[4] = f2bf(b.x); o[5] = f2bf(b.y); o[6] = f2bf(b.z); o[7] = f2bf(b.w);
  xb[i] = o;
}

// ---------- R1: partial sums over S for router mean-pool ----------
__global__ __launch_bounds__(256) void k_xsum(const float* __restrict__ x,
                                              float* __restrict__ xsum) {
  int b = blockIdx.x, sc = blockIdx.z;
  int h = blockIdx.y * 256 + threadIdx.x;
  float s = 0.f;
  const float* p = x + ((size_t)(b * 512 + sc * 128)) * 768 + h;
  for (int i = 0; i < 128; ++i) s += p[(size_t)i * 768];
  xsum[(sc * 32 + b) * 768 + h] = s;
}

// ---------- R2: router logits + argmax (block per sample) ----------
__global__ __launch_bounds__(256) void k_route(const float* __restrict__ xsum,
                                               const float* __restrict__ sw,
                                               const float* __restrict__ sb,
                                               int* __restrict__ route) {
  int b = blockIdx.x, t = threadIdx.x;
  float l0 = 0.f, l1 = 0.f;
  for (int h = t; h < 768; h += 256) {
    float xm = (xsum[(0 * 32 + b) * 768 + h] + xsum[(1 * 32 + b) * 768 + h] +
                xsum[(2 * 32 + b) * 768 + h] + xsum[(3 * 32 + b) * 768 + h]) *
               (1.f / 512.f);
    l0 += xm * sw[h * 2 + 0];
    l1 += xm * sw[h * 2 + 1];
  }
#pragma unroll
  for (int off = 32; off; off >>= 1) {
    l0 += __shfl_down(l0, off);
    l1 += __shfl_down(l1, off);
  }
  __shared__ float s0[4], s1[4];
  int w = t >> 6;
  if ((t & 63) == 0) { s0[w] = l0; s1[w] = l1; }
  __syncthreads();
  if (t == 0) {
    float a0 = sb[0] + s0[0] + s0[1] + s0[2] + s0[3];
    float a1 = sb[1] + s1[0] + s1[1] + s1[2] + s1[3];
    route[b] = (a1 > a0) ? 1 : 0;  // softmax monotonic; ties -> argmax picks 0
  }
}

// ---------- P2: transpose+convert W matrices -> W^T bf16 ----------
__global__ __launch_bounds__(256) void k_wt(const float* __restrict__ cwq, const float* __restrict__ cwk,
                                            const float* __restrict__ cwv, const float* __restrict__ cwo,
                                            const float* __restrict__ ewo,
                                            const float* __restrict__ ewq, const float* __restrict__ ewk,
                                            const float* __restrict__ ewv,
                                            unsigned short* __restrict__ wtc,
                                            unsigned short* __restrict__ wtewo,
                                            unsigned short* __restrict__ wtexp) {
  __shared__ float t[32][33];
  int z = blockIdx.z;
  const float* src;
  unsigned short* dst;
  if (z < 4) {
    src = (z == 0) ? cwq : (z == 1) ? cwk : (z == 2) ? cwv : cwo;
    dst = wtc + (size_t)z * 589824;
  } else if (z < 6) {
    src = ewo + (size_t)(z - 4) * 589824;
    dst = wtewo + (size_t)(z - 4) * 589824;
  } else {
    int mat = (z - 6) >> 1, e = (z - 6) & 1;
    src = ((mat == 0) ? ewq : (mat == 1) ? ewk : ewv) + (size_t)e * 589824;
    dst = wtexp + (size_t)(mat * 2 + e) * 589824;
  }
  int k0 = blockIdx.x * 32, n0 = blockIdx.y * 32;
  int tid = threadIdx.x;
#pragma unroll
  for (int i = 0; i < 4; ++i) {
    int lin = tid + 256 * i; int kk = lin >> 5, nn = lin & 31;
    t[kk][nn] = src[(size_t)(k0 + kk) * 768 + n0 + nn];
  }
  __syncthreads();
#pragma unroll
  for (int i = 0; i < 4; ++i) {
    int lin = tid + 256 * i; int nn = lin >> 5, kk = lin & 31;
    dst[(size_t)(n0 + nn) * 768 + k0 + kk] = f2bf(t[kk][nn]);
  }
}

// ---------- P3a: convert A (LoRA down) fp32 -> bf16, layout [768][128] ----------
__global__ __launch_bounds__(256) void k_acvt(const float* __restrict__ eaq, const float* __restrict__ eak,
                                              const float* __restrict__ eav,
                                              unsigned short* __restrict__ abt) {
  int z = blockIdx.z;  // mat*2+e
  int mat = z >> 1, e = z & 1;
  const float* src = ((mat == 0) ? eaq : (mat == 1) ? eak : eav) + (size_t)e * 98304;
  unsigned short* dst = abt + (size_t)z * 98304;
  int i = blockIdx.x * 256 + threadIdx.x;
  const float* p = src + (size_t)i * 8;
  float4 a = *(const float4*)p;
  float4 b = *(const float4*)(p + 4);
  u16x8 o;
  o[0] = f2bf(a.x); o[1] = f2bf(a.y); o[2] = f2bf(a.z); o[3] = f2bf(a.w);
  o[4] = f2bf(b.x); o[5] = f2bf(b.y); o[6] = f2bf(b.z); o[7] = f2bf(b.w);
  *(u16x8*)(dst + (size_t)i * 8) = o;
}

// ---------- P3b: transpose G [128][768] -> G^T bf16 [768][128] ----------
__global__ __launch_bounds__(256) void k_gtr(const float* __restrict__ egq, const float* __restrict__ egk,
                                             const float* __restrict__ egv,
                                             unsigned short* __restrict__ gtb) {
  __shared__ float t[32][33];
  int z = blockIdx.z;  // mat*2+e
  int mat = z >> 1, e = z & 1;
  const float* src = ((mat == 0) ? egq : (mat == 1) ? egk : egv) + (size_t)e * 98304;
  unsigned short* dst = gtb + (size_t)z * 98304;
  int n0 = blockIdx.x * 32, r0 = blockIdx.y * 32;
  int tid = threadIdx.x;
#pragma unroll
  for (int i = 0; i < 4; ++i) {
    int lin = tid + 256 * i; int rr = lin >> 5, nn = lin & 31;
    t[rr][nn] = src[(size_t)(r0 + rr) * 768 + n0 + nn];
  }
  __syncthreads();
#pragma unroll
  for (int i = 0; i < 4; ++i) {
    int lin = tid + 256 * i; int nn = lin >> 5, rr = lin & 31;
    dst[(size_t)(n0 + nn) * 128 + r0 + rr] = f2bf(t[rr][nn]);
  }
}

// ---------- P4: merged expert weight via MFMA: wte = W^T + G^T @ A^B  ----------
__global__ __launch_bounds__(256) void k_mergemm(const unsigned short* __restrict__ gtb,
                                                 const unsigned short* __restrict__ abt,
                                                 const unsigned short* __restrict__ wtexp,
                                                 unsigned short* __restrict__ wte) {
  const int z = blockIdx.z;  // mat*2+e
  const int m0 = blockIdx.x * 128, n0 = blockIdx.y * 128;
  const unsigned short* Am = gtb + (size_t)z * 98304;
  const unsigned short* Bm = abt + (size_t)z * 98304;
  const unsigned short* Wt = wtexp + (size_t)z * 589824;
  unsigned short* dst = wte + (size_t)z * 589824;
  __shared__ __align__(16) unsigned short As[128 * 32];
  __shared__ __align__(16) unsigned short Bs[128 * 32];
  const int tid = threadIdx.x, w = tid >> 6, lane = tid & 63, g = lane >> 4, l15 = lane & 15;
  const int wr = (w >> 1) * 64, wc = (w & 1) * 64;
  f32x4 acc[4][4] = {};
  for (int k0 = 0; k0 < 128; k0 += 32) {
#pragma unroll
    for (int c = 0; c < 2; ++c) {
      int o = (w * 2 + c) * 1024 + lane * 16;
      int row = o >> 6, chunk = (o >> 4) & 3;
      gload_lds16(Am + (size_t)(m0 + row) * 128 + k0 + (chunk << 3),
                  (char*)As + (w * 2 + c) * 1024);
      gload_lds16(Bm + (size_t)(n0 + row) * 128 + k0 + (chunk << 3),
                  (char*)Bs + (w * 2 + c) * 1024);
    }
    __syncthreads();
    bf16x8 af[4], bfr[4];
#pragma unroll
    for (int mi = 0; mi < 4; ++mi) {
      int row = wr + mi * 16 + l15;
      af[mi] = *(const bf16x8*)((const char*)As + row * 64 + (g << 4));
    }
#pragma unroll
    for (int ni = 0; ni < 4; ++ni) {
      int row = wc + ni * 16 + l15;
      bfr[ni] = *(const bf16x8*)((const char*)Bs + row * 64 + (g << 4));
    }
#pragma unroll
    for (int mi = 0; mi < 4; ++mi)
#pragma unroll
      for (int ni = 0; ni < 4; ++ni)
        acc[mi][ni] = mfma16(af[mi], bfr[ni], acc[mi][ni]);
    __syncthreads();
  }
#pragma unroll
  for (int ni = 0; ni < 4; ++ni) {
    int col = n0 + wc + ni * 16 + l15;
#pragma unroll
    for (int mi = 0; mi < 4; ++mi) {
#pragma unroll
      for (int r = 0; r < 4; ++r) {
        int row = m0 + wr + mi * 16 + 4 * g + r;
        size_t idx = (size_t)row * 768 + col;
        dst[idx] = f2bf(acc[mi][ni][r] + bf2f(Wt[idx]));
      }
    }
  }
}

// ---------- shared 256x256 phase helper (r10/r11-verified) ----------
template <int MH, int KK, bool LOADB>
DEVINL void qphase(const unsigned short* As, const unsigned short* Bs,
                   bf16x8 (&bfr)[4], f32x4 (&acc)[8][4],
                   int wr, int wc, int g, int l15) {
  if (LOADB) {
#pragma unroll
    for (int nj = 0; nj < 4; ++nj) {
      int row = wc + nj * 16 + l15;
      bfr[nj] = *(const bf16x8*)((const char*)Bs + row * 128 + (((KK * 4 + g) ^ (row & 7)) << 4));
    }
  }
  bf16x8 af[4];
#pragma unroll
  for (int mi = 0; mi < 4; ++mi) {
    int row = wr + MH * 64 + mi * 16 + l15;
    af[mi] = *(const bf16x8*)((const char*)As + row * 128 + (((KK * 4 + g) ^ (row & 7)) << 4));
  }
  __builtin_amdgcn_s_setprio(1);
#pragma unroll
  for (int mi = 0; mi < 4; ++mi)
#pragma unroll
    for (int nj = 0; nj < 4; ++nj)
      acc[MH * 4 + mi][nj] = mfma16(af[mi], bfr[nj], acc[MH * 4 + mi][nj]);
  __builtin_amdgcn_s_setprio(0);
}

// ---------- G1: QKV GEMM 256x256, BK=64, phased; z = mat + 3*(expert-base) ----------
__global__ __launch_bounds__(512, 2) void k_gemm_qkv(
    const unsigned short* __restrict__ xb, const unsigned short* __restrict__ wtc,
    const unsigned short* __restrict__ wte,
    const float* __restrict__ cbq, const float* __restrict__ cbk, const float* __restrict__ cbv,
    const float* __restrict__ ebq, const float* __restrict__ ebk, const float* __restrict__ ebv,
    const int* __restrict__ route,
    unsigned short* __restrict__ qC, unsigned short* __restrict__ kC, unsigned short* __restrict__ vC,
    unsigned short* __restrict__ qE, unsigned short* __restrict__ kE, unsigned short* __restrict__ vE,
    int base_expert) {
  extern __shared__ __align__(16) unsigned short smem[];  // 131072 B
  const int m0 = blockIdx.x * 256, n0 = blockIdx.y * 256;
  const int mat = blockIdx.z % 3;
  const int expert = base_expert + blockIdx.z / 3;
  const int b = m0 >> 9;
  const unsigned short* wt;
  const float* bias;
  if (!expert) {
    wt = wtc + (size_t)mat * 589824;
    bias = (mat == 0) ? cbq : (mat == 1) ? cbk : cbv;
  } else {
    int e = route[b];
    wt = wte + (size_t)(mat * 2 + e) * 589824;
    bias = ((mat == 0) ? ebq : (mat == 1) ? ebk : ebv) + e * 768;
  }
  unsigned short* outq = expert ? qE : qC;
  unsigned short* outk = expert ? kE : kC;
  unsigned short* vt   = expert ? vE : vC;
  const int tid = threadIdx.x, w = tid >> 6, lane = tid & 63, g = lane >> 4, l15 = lane & 15;
  const int wr = (w >> 2) * 128, wc = (w & 3) * 64;
  const int srow = lane >> 3, sslot = lane & 7;
  f32x4 acc[8][4] = {};

  auto stage_half = [&](int buf, int t, int h) {
    const unsigned short* src = (h < 2) ? xb : wt;
    int rowbase = (h < 2) ? (m0 + h * 128) : (n0 + (h - 2) * 128);
    unsigned short* lb = smem + buf * 32768 + ((h < 2) ? (h * 8192) : (16384 + (h - 2) * 8192));
    int k0 = t * 64;
#pragma unroll
    for (int c = 0; c < 2; ++c) {
      int rl = (w * 2 + c) * 8 + srow;
      int gc = (sslot ^ (rl & 7)) << 3;
      gload_lds16(src + (size_t)(rowbase + rl) * 768 + k0 + gc,
                  (char*)lb + (w * 2 + c) * 1024);
    }
  };

#pragma unroll
  for (int h = 0; h < 4; ++h) stage_half(0, 0, h);
  int cur = 0;
  for (int t = 0; t < 12; ++t) {
    const int nxt = cur ^ 1;
    const int tn = (t + 1 < 12) ? (t + 1) : 0;
    const unsigned short* As = smem + cur * 32768;
    const unsigned short* Bs = smem + cur * 32768 + 16384;
    bf16x8 bfr[4];
    stage_half(nxt, tn, 0);
    stage_half(nxt, tn, 2);
    asm volatile("s_waitcnt vmcnt(4)" ::: "memory");
    asm volatile("s_barrier" ::: "memory");
    qphase<0, 0, true>(As, Bs, bfr, acc, wr, wc, g, l15);
    stage_half(nxt, tn, 1);
    stage_half(nxt, tn, 3);
    asm volatile("s_barrier" ::: "memory");
    qphase<1, 0, false>(As, Bs, bfr, acc, wr, wc, g, l15);
    asm volatile("s_barrier" ::: "memory");
    qphase<0, 1, true>(As, Bs, bfr, acc, wr, wc, g, l15);
    asm volatile("s_barrier" ::: "memory");
    qphase<1, 1, false>(As, Bs, bfr, acc, wr, wc, g, l15);
    asm volatile("s_barrier" ::: "memory");
    cur = nxt;
  }
  __syncthreads();

  if (mat != 2) {
    unsigned short* pw = smem + w * 8192;
#pragma unroll
    for (int nj = 0; nj < 4; ++nj) {
      float bv = bias[n0 + wc + nj * 16 + l15];
#pragma unroll
      for (int fr = 0; fr < 8; ++fr)
#pragma unroll
        for (int r = 0; r < 4; ++r) {
          int lr = fr * 16 + 4 * g + r;
          int lc = nj * 16 + l15;
          pw[lr * 64 + (((lc >> 3) ^ (lr & 7)) << 3) + (lc & 7)] =
              f2bf(acc[fr][nj][r] + bv);
        }
    }
    unsigned short* dst = (mat == 0) ? outq : outk;
#pragma unroll
    for (int i = 0; i < 16; ++i) {
      int ci = i * 64 + lane;
      int row = ci >> 3;
      int c8 = ci & 7;
      u16x8 v = *(const u16x8*)(pw + row * 64 + ((c8 ^ (row & 7)) << 3));
      *(u16x8*)(dst + (size_t)(m0 + wr + row) * 768 + n0 + wc + c8 * 8) = v;
    }
  } else {
    unsigned short* Ts2 = smem;  // [128 cols][264]
#pragma unroll
    for (int p = 0; p < 2; ++p) {
      if (((w & 3) >> 1) == p) {
#pragma unroll
        for (int nj = 0; nj < 4; ++nj) {
          int ccl = ((w & 3) & 1) * 64 + nj * 16 + l15;
          float bv = bias[n0 + p * 128 + ccl];
#pragma unroll
          for (int fr = 0; fr < 8; ++fr)
#pragma unroll
            for (int r = 0; r < 4; ++r) {
              int row = wr + fr * 16 + 4 * g + r;
              Ts2[ccl * 264 + row] = f2bf(acc[fr][nj][r] + bv);
            }
        }
      }
      __syncthreads();
#pragma unroll
      for (int i = 0; i < 8; ++i) {
        int ci = tid + 512 * i, cc = ci >> 5, j = ci & 31;
        u16x8 v = *(const u16x8*)(Ts2 + cc * 264 + j * 8);
        int colg = n0 + p * 128 + cc;
        int head = colg >> 6, dh = colg & 63;
        *(u16x8*)(vt + ((size_t)((b * 12 + head) * 64 + dh)) * 512 + (m0 & 511) + j * 8) = v;
      }
      __syncthreads();
    }
  }
}

// ---------- A1: flash attention; double-buffered K/V, counted vmcnt (r13) ----------
// Per kt: issue stage(t+1) into buf^1 FIRST; s_waitcnt vmcnt(2) (2 newest = t+1's
// loads; all older drained => tile t resident); raw s_barrier; compute qs=0,1 on
// buf; end barrier (all readers of buf done before next iter stages into it).
// Mask bias preloaded once into mk2[512] (removes per-tile divergent load).
__global__ __launch_bounds__(512) void k_attn(
    const unsigned short* __restrict__ Q0, const unsigned short* __restrict__ K0,
    const unsigned short* __restrict__ V0, unsigned short* __restrict__ ctx0,
    const unsigned short* __restrict__ Q1, const unsigned short* __restrict__ K1,
    const unsigned short* __restrict__ V1, unsigned short* __restrict__ ctx1,
    const float* __restrict__ mask) {
  const int qh = blockIdx.x, h = blockIdx.y;
  const int b = blockIdx.z & 31, path = blockIdx.z >> 5;
  const unsigned short* Q = path ? Q1 : Q0;
  const unsigned short* K = path ? K1 : K0;
  const unsigned short* Vt = path ? V1 : V0;
  unsigned short* ctx = path ? ctx1 : ctx0;
  const int tid = threadIdx.x, w = tid >> 6, lane = tid & 63, g = lane >> 4, l15 = lane & 15;
  const int qbase = b * 512 + qh * 256 + w * 32;
  bf16x8 qf[2][2];
#pragma unroll
  for (int qs = 0; qs < 2; ++qs) {
    const unsigned short* qp = Q + (size_t)(qbase + qs * 16 + l15) * 768 + h * 64;
    qf[qs][0] = *(const bf16x8*)(qp + g * 8);
    qf[qs][1] = *(const bf16x8*)(qp + 32 + g * 8);
  }
  __shared__ __align__(16) unsigned short Ks[2][64 * 64];
  __shared__ __align__(16) unsigned short Vs[2][64 * 64];
  __shared__ __align__(16) unsigned short Pl[8 * 16 * 64];
  __shared__ float mk2[512];
  float lsum[2] = {0.f, 0.f};
  f32x4 acc[2][4] = {};
  const unsigned short* Kb = K + (size_t)(b * 512) * 768 + h * 64;
  const unsigned short* Vb = Vt + (size_t)((b * 12 + h) * 64) * 512;
  unsigned short* pws = Pl + w * 1024;
  const int srow = w * 8 + (lane >> 3);
  const int schunk = lane & 7;
  const int ssw = (schunk ^ (srow & 7)) << 3;
  const float C = 0.125f * 1.44269504f;

  auto stage = [&](int buf, int kt) {
    const int kv0 = kt * 64;
    gload_lds16(Kb + (size_t)(kv0 + srow) * 768 + ssw, (char*)Ks[buf] + w * 1024);
    gload_lds16(Vb + (size_t)srow * 512 + kv0 + ssw, (char*)Vs[buf] + w * 1024);
  };

  // prologue: tile 0 into buf 0 + mask bias table; syncthreads drains both
  stage(0, 0);
  mk2[tid] = (1.f - mask[b * 512 + tid]) * (-14426.9504f);
  __syncthreads();

  int cur = 0;
  for (int kt = 0; kt < 8; ++kt) {
    const int kv0 = kt * 64;
    stage(cur ^ 1, (kt + 1 < 8) ? (kt + 1) : 0);  // kt=7 stages dummy (uniform vmcnt)
    asm volatile("s_waitcnt vmcnt(2)" ::: "memory");
    asm volatile("s_barrier" ::: "memory");
    const unsigned short* Kc = Ks[cur];
    const unsigned short* Vc = Vs[cur];
#pragma unroll
    for (int qs = 0; qs < 2; ++qs) {
      f32x4 sf[4];
#pragma unroll
      for (int mb = 0; mb < 4; ++mb) {
        int row = mb * 16 + l15;
        bf16x8 ka  = *(const bf16x8*)(Kc + row * 64 + ((g ^ (row & 7)) << 3));
        bf16x8 kb2 = *(const bf16x8*)(Kc + row * 64 + (((g + 4) ^ (row & 7)) << 3));
        f32x4 z = {0.f, 0.f, 0.f, 0.f};
        z = mfma16(ka, qf[qs][0], z);
        z = mfma16(kb2, qf[qs][1], z);
        sf[mb] = z;
      }
      float p[16];
      float psum = 0.f;
#pragma unroll
      for (int mb = 0; mb < 4; ++mb)
#pragma unroll
        for (int r = 0; r < 4; ++r) {
          float e2 = exp2f(fmaf(sf[mb][r], C, mk2[kv0 + mb * 16 + g * 4 + r]));
          p[mb * 4 + r] = e2;
          psum += e2;
        }
      lsum[qs] += psum;
#pragma unroll
      for (int mb = 0; mb < 4; ++mb)
#pragma unroll
        for (int hh = 0; hh < 2; ++hh) {
          unsigned val = (unsigned)f2bf(p[mb * 4 + 2 * hh]) |
                         ((unsigned)f2bf(p[mb * 4 + 2 * hh + 1]) << 16);
          int off = mb * 16 + 4 * g + 2 * hh;
          int cw = (off >> 3) ^ (l15 & 7);
          *(unsigned*)(pws + l15 * 64 + (cw << 3) + (off & 7)) = val;
        }
#pragma unroll
      for (int ks = 0; ks < 2; ++ks) {
        bf16x8 pf = *(const bf16x8*)(pws + l15 * 64 + (((4 * ks + g) ^ (l15 & 7)) << 3));
#pragma unroll
        for (int d = 0; d < 4; ++d) {
          int row = d * 16 + l15;
          bf16x8 vf = *(const bf16x8*)(Vc + row * 64 + (((g + 4 * ks) ^ (row & 7)) << 3));
          acc[qs][d] = mfma16(vf, pf, acc[qs][d]);
        }
      }
    }
    asm volatile("s_barrier" ::: "memory");  // readers of buf[cur] done before next stage into it
    cur ^= 1;
  }
#pragma unroll
  for (int qs = 0; qs < 2; ++qs) {
    float t = lsum[qs];
    t += __shfl_xor(t, 16);
    t += __shfl_xor(t, 32);
    float inv = 1.f / t;
    unsigned short* op = ctx + (size_t)(qbase + qs * 16 + l15) * 768 + h * 64;
#pragma unroll
    for (int d = 0; d < 4; ++d) {
      u16x4 o4;
#pragma unroll
      for (int r = 0; r < 4; ++r) o4[r] = f2bf(acc[qs][d][r] * inv);
      *(u16x4*)(op + d * 16 + 4 * g) = o4;
    }
  }
}

// ---------- G2: fused out-proj, 256x256 tile, K=1536 dual-source, phased ----------
__global__ __launch_bounds__(512, 2) void k_gemm_out(
    const unsigned short* __restrict__ ctxc, const unsigned short* __restrict__ ctxe,
    const unsigned short* __restrict__ woc, const unsigned short* __restrict__ woe,
    const float* __restrict__ cbo, const float* __restrict__ ebo,
    const int* __restrict__ route, float* __restrict__ out) {
  extern __shared__ __align__(16) unsigned short smem[];  // 131072 B
  const int m0 = blockIdx.x * 256, n0 = blockIdx.y * 256;
  const int b = m0 >> 9;
  const int e = route[b];
  const int tid = threadIdx.x, w = tid >> 6, lane = tid & 63, g = lane >> 4, l15 = lane & 15;
  const int wr = (w >> 2) * 128, wc = (w & 3) * 64;
  const int srow = lane >> 3, sslot = lane & 7;
  f32x4 acc[8][4] = {};

  auto stage_half = [&](int buf, int t, int h) {
    const unsigned short* src =
        (h < 2) ? ((t < 12) ? ctxc : ctxe)
                : ((t < 12) ? woc : (woe + (size_t)e * 589824));
    int rowbase = (h < 2) ? (m0 + h * 128) : (n0 + (h - 2) * 128);
    unsigned short* lb = smem + buf * 32768 + ((h < 2) ? (h * 8192) : (16384 + (h - 2) * 8192));
    int k0 = (t % 12) * 64;
#pragma unroll
    for (int c = 0; c < 2; ++c) {
      int rl = (w * 2 + c) * 8 + srow;
      int gc = (sslot ^ (rl & 7)) << 3;
      gload_lds16(src + (size_t)(rowbase + rl) * 768 + k0 + gc,
                  (char*)lb + (w * 2 + c) * 1024);
    }
  };

#pragma unroll
  for (int h = 0; h < 4; ++h) stage_half(0, 0, h);
  int cur = 0;
  for (int t = 0; t < 24; ++t) {
    const int nxt = cur ^ 1;
    const int tn = (t + 1 < 24) ? (t + 1) : 0;
    const unsigned short* As = smem + cur * 32768;
    const unsigned short* Bs = smem + cur * 32768 + 16384;
    bf16x8 bfr[4];
    stage_half(nxt, tn, 0);
    stage_half(nxt, tn, 2);
    asm volatile("s_waitcnt vmcnt(4)" ::: "memory");
    asm volatile("s_barrier" ::: "memory");
    qphase<0, 0, true>(As, Bs, bfr, acc, wr, wc, g, l15);
    stage_half(nxt, tn, 1);
    stage_half(nxt, tn, 3);
    asm volatile("s_barrier" ::: "memory");
    qphase<1, 0, false>(As, Bs, bfr, acc, wr, wc, g, l15);
    asm volatile("s_barrier" ::: "memory");
    qphase<0, 1, true>(As, Bs, bfr, acc, wr, wc, g, l15);
    asm volatile("s_barrier" ::: "memory");
    qphase<1, 1, false>(As, Bs, bfr, acc, wr, wc, g, l15);
    asm volatile("s_barrier" ::: "memory");
    cur = nxt;
  }
  __syncthreads();

  float* fs = (float*)smem;
#pragma unroll
  for (int p = 0; p < 4; ++p) {
    if ((w >> 2) == (p >> 1)) {
#pragma unroll
      for (int nj = 0; nj < 4; ++nj) {
        int lc = wc + nj * 16 + l15;
        int col = n0 + lc;
        float bsum = cbo[col] + ebo[e * 768 + col];
#pragma unroll
        for (int fi = 0; fi < 4; ++fi) {
          int fr = (p & 1) * 4 + fi;
#pragma unroll
          for (int r = 0; r < 4; ++r) {
            int lr = fi * 16 + 4 * g + r;
            fs[lr * 256 + (((lc >> 2) ^ (lr & 7)) << 2) + (lc & 3)] =
                acc[fr][nj][r] + bsum;
          }
        }
      }
    }
    __syncthreads();
#pragma unroll
    for (int j = 0; j < 8; ++j) {
      int ci = j * 512 + tid;
      int row = ci >> 6, sl = ci & 63;
      f32x4 v = *(const f32x4*)(fs + row * 256 + ((sl ^ (row & 7)) << 2));
      *(f32x4*)(out + (size_t)(m0 + p * 64 + row) * 768 + n0 + sl * 4) = v;
    }
    __syncthreads();
  }
}

extern "C" void kernel_launch(void* const* d_in, const int* in_sizes, int n_in,
                              void* d_out, int out_size, void* d_ws, size_t ws_size,
                              hipStream_t stream) {
  const float* x    = (const float*)d_in[0];
  const float* sw   = (const float*)d_in[1];
  const float* sb   = (const float*)d_in[2];
  const float* cwq  = (const float*)d_in[3];
  const float* cbq  = (const float*)d_in[4];
  const float* cwk  = (const float*)d_in[5];
  const float* cbk  = (const float*)d_in[6];
  const float* cwv  = (const float*)d_in[7];
  const float* cbv  = (const float*)d_in[8];
  const float* cwo  = (const float*)d_in[9];
  const float* cbo  = (const float*)d_in[10];
  const float* ewq  = (const float*)d_in[11];
  const float* ebq  = (const float*)d_in[12];
  const float* eaq  = (const float*)d_in[13];
  const float* egq  = (const float*)d_in[14];
  const float* ewk  = (const float*)d_in[15];
  const float* ebk  = (const float*)d_in[16];
  const float* eak  = (const float*)d_in[17];
  const float* egk  = (const float*)d_in[18];
  const float* ewv  = (const float*)d_in[19];
  const float* ebv  = (const float*)d_in[20];
  const float* eav  = (const float*)d_in[21];
  const float* egv  = (const float*)d_in[22];
  const float* ewo  = (const float*)d_in[23];
  const float* ebo  = (const float*)d_in[24];
  const float* amask = (const float*)d_in[25];
  (void)in_sizes; (void)n_in; (void)out_size;

  (void)hipFuncSetAttribute(reinterpret_cast<const void*>(k_gemm_qkv),
                            hipFuncAttributeMaxDynamicSharedMemorySize, 131072);
  (void)hipFuncSetAttribute(reinterpret_cast<const void*>(k_gemm_out),
                            hipFuncAttributeMaxDynamicSharedMemorySize, 131072);

  char* ws = (char*)d_ws;
  const size_t SZ = 25165824;  // 16384*768*2 bytes
  const size_t MERGED_NEED = 8 * SZ + 4718592 + 7077888 + 2359296 + 393216 + 256;
  const bool merged = (ws_size >= MERGED_NEED);

  unsigned short *xb, *qbC, *kC, *vC, *qbE, *kE, *vE, *ctxc, *ctxe;
  char* wbase;
  if (merged) {
    xb   = (unsigned short*)(ws);
    qbC  = (unsigned short*)(ws + SZ);
    kC   = (unsigned short*)(ws + 2 * SZ);
    vC   = (unsigned short*)(ws + 3 * SZ);
    qbE  = (unsigned short*)(ws + 4 * SZ);
    kE   = (unsigned short*)(ws + 5 * SZ);
    vE   = (unsigned short*)(ws + 6 * SZ);
    ctxc = (unsigned short*)(ws + 7 * SZ);
    ctxe = (unsigned short*)(ws);  // alias of xb (dead after merged qkv)
    wbase = ws + 8 * SZ;
  } else {
    xb   = (unsigned short*)(ws);
    qbC  = qbE = (unsigned short*)(ws + SZ);
    kC   = kE  = (unsigned short*)(ws + 2 * SZ);
    vC   = vE  = (unsigned short*)(ws + 3 * SZ);
    ctxc = (unsigned short*)(ws + 4 * SZ);
    ctxe = (unsigned short*)(ws);  // alias of xb
    wbase = ws + 5 * SZ;
  }
  unsigned short* wtc   = (unsigned short*)(wbase);
  unsigned short* wte   = (unsigned short*)(wbase + 4718592);
  unsigned short* wtewo = (unsigned short*)(wbase + 4718592 + 7077888);
  float* xsum           = (float*)(wbase + 4718592 + 7077888 + 2359296);
  int* route            = (int*)(wbase + 4718592 + 7077888 + 2359296 + 393216);
  unsigned short* abt   = (unsigned short*)(ws + SZ);
  unsigned short* gtb   = (unsigned short*)(ws + SZ + 1179648);
  unsigned short* wtexp = (unsigned short*)(ws + SZ + 2359296);

  k_cvt<<<6144, 256, 0, stream>>>(x, (u16x8*)xb);
  k_xsum<<<dim3(32, 3, 4), 256, 0, stream>>>(x, xsum);
  k_route<<<32, 256, 0, stream>>>(xsum, sw, sb, route);
  k_wt<<<dim3(24, 24, 12), 256, 0, stream>>>(cwq, cwk, cwv, cwo, ewo, ewq, ewk, ewv,
                                             wtc, wtewo, wtexp);
  k_acvt<<<dim3(48, 1, 6), 256, 0, stream>>>(eaq, eak, eav, abt);
  k_gtr<<<dim3(24, 4, 6), 256, 0, stream>>>(egq, egk, egv, gtb);
  k_mergemm<<<dim3(6, 6, 6), 256, 0, stream>>>(gtb, abt, wtexp, wte);

  if (merged) {
    k_gemm_qkv<<<dim3(64, 3, 6), 512, 131072, stream>>>(
        xb, wtc, wte, cbq, cbk, cbv, ebq, ebk, ebv, route,
        qbC, kC, vC, qbE, kE, vE, 0);
    k_attn<<<dim3(2, 12, 64), 512, 0, stream>>>(qbC, kC, vC, ctxc,
                                                qbE, kE, vE, ctxe, amask);
  } else {
    k_gemm_qkv<<<dim3(64, 3, 3), 512, 131072, stream>>>(
        xb, wtc, wte, cbq, cbk, cbv, ebq, ebk, ebv, route,
        qbC, kC, vC, qbC, kC, vC, 0);
    k_attn<<<dim3(2, 12, 32), 512, 0, stream>>>(qbC, kC, vC, ctxc,
                                                qbC, kC, vC, ctxc, amask);
    k_gemm_qkv<<<dim3(64, 3, 3), 512, 131072, stream>>>(
        xb, wtc, wte, cbq, cbk, cbv, ebq, ebk, ebv, route,
        qbC, kC, vC, qbC, kC, vC, 1);
    k_attn<<<dim3(2, 12, 32), 512, 0, stream>>>(qbC, kC, vC, ctxe,
                                                qbC, kC, vC, ctxe, amask);
  }
  k_gemm_out<<<dim3(64, 3), 512, 131072, stream>>>(ctxc, ctxe, wtc + 3 * 589824, wtewo,
                                                   cbo, ebo, route, (float*)d_out);
}

// Round 14
// 321.820 us; speedup vs baseline: 1.0988x; 1.0988x over previous
//
#include <hip/hip_runtime.h>
#include <hip/hip_bf16.h>

#define DEVINL __device__ __forceinline__

typedef __bf16 bf16x8 __attribute__((ext_vector_type(8)));
typedef float f32x4 __attribute__((ext_vector_type(4)));
typedef unsigned int u32x4 __attribute__((ext_vector_type(4)));
typedef unsigned short u16x8 __attribute__((ext_vector_type(8)));
typedef unsigned short u16x4 __attribute__((ext_vector_type(4)));

DEVINL unsigned short f2bf(float f) {
  __hip_bfloat16 h = __float2bfloat16(f);
  return __builtin_bit_cast(unsigned short, h);
}

DEVINL float bf2f(unsigned short u) {
  return __builtin_bit_cast(float, ((unsigned)u) << 16);
}

DEVINL f32x4 mfma16(bf16x8 a, bf16x8 b, f32x4 c) {
  return __builtin_amdgcn_mfma_f32_16x16x32_bf16(a, b, c, 0, 0, 0);
}

DEVINL void gload_lds16(const void* g, void* l) {
  __builtin_amdgcn_global_load_lds(
      (const __attribute__((address_space(1))) unsigned int*)g,
      (__attribute__((address_space(3))) unsigned int*)l, 16, 0, 0);
}

// ---------- P0: x f32 -> bf16 ----------
__global__ __launch_bounds__(256) void k_cvt(const float* __restrict__ x,
                                             u16x8* __restrict__ xb) {
  int i = blockIdx.x * 256 + threadIdx.x;
  const float* p = x + (size_t)i * 8;
  float4 a = *(const float4*)p;
  float4 b = *(const float4*)(p + 4);
  u16x8 o;
  o[0] = f2bf(a.x); o[1] = f2bf(a.y); o[2] = f2bf(a.z); o[3] = f2bf(a.w);
  o[4] = f2bf(b.x); o[5] = f2bf(b.y); o[6] = f2bf(b.z); o[7] = f2bf(b.w);
  xb[i] = o;
}

// ---------- R1: partial sums over S for router mean-pool ----------
__global__ __launch_bounds__(256) void k_xsum(const float* __restrict__ x,
                                              float* __restrict__ xsum) {
  int b = blockIdx.x, sc = blockIdx.z;
  int h = blockIdx.y * 256 + threadIdx.x;
  float s = 0.f;
  const float* p = x + ((size_t)(b * 512 + sc * 128)) * 768 + h;
  for (int i = 0; i < 128; ++i) s += p[(size_t)i * 768];
  xsum[(sc * 32 + b) * 768 + h] = s;
}

// ---------- R2: router logits + argmax (block per sample) ----------
__global__ __launch_bounds__(256) void k_route(const float* __restrict__ xsum,
                                               const float* __restrict__ sw,
                                               const float* __restrict__ sb,
                                               int* __restrict__ route) {
  int b = blockIdx.x, t = threadIdx.x;
  float l0 = 0.f, l1 = 0.f;
  for (int h = t; h < 768; h += 256) {
    float xm = (xsum[(0 * 32 + b) * 768 + h] + xsum[(1 * 32 + b) * 768 + h] +
                xsum[(2 * 32 + b) * 768 + h] + xsum[(3 * 32 + b) * 768 + h]) *
               (1.f / 512.f);
    l0 += xm * sw[h * 2 + 0];
    l1 += xm * sw[h * 2 + 1];
  }
#pragma unroll
  for (int off = 32; off; off >>= 1) {
    l0 += __shfl_down(l0, off);
    l1 += __shfl_down(l1, off);
  }
  __shared__ float s0[4], s1[4];
  int w = t >> 6;
  if ((t & 63) == 0) { s0[w] = l0; s1[w] = l1; }
  __syncthreads();
  if (t == 0) {
    float a0 = sb[0] + s0[0] + s0[1] + s0[2] + s0[3];
    float a1 = sb[1] + s1[0] + s1[1] + s1[2] + s1[3];
    route[b] = (a1 > a0) ? 1 : 0;  // softmax monotonic; ties -> argmax picks 0
  }
}

// ---------- P2: transpose+convert W matrices -> W^T bf16 ----------
__global__ __launch_bounds__(256) void k_wt(const float* __restrict__ cwq, const float* __restrict__ cwk,
                                            const float* __restrict__ cwv, const float* __restrict__ cwo,
                                            const float* __restrict__ ewo,
                                            const float* __restrict__ ewq, const float* __restrict__ ewk,
                                            const float* __restrict__ ewv,
                                            unsigned short* __restrict__ wtc,
                                            unsigned short* __restrict__ wtewo,
                                            unsigned short* __restrict__ wtexp) {
  __shared__ float t[32][33];
  int z = blockIdx.z;
  const float* src;
  unsigned short* dst;
  if (z < 4) {
    src = (z == 0) ? cwq : (z == 1) ? cwk : (z == 2) ? cwv : cwo;
    dst = wtc + (size_t)z * 589824;
  } else if (z < 6) {
    src = ewo + (size_t)(z - 4) * 589824;
    dst = wtewo + (size_t)(z - 4) * 589824;
  } else {
    int mat = (z - 6) >> 1, e = (z - 6) & 1;
    src = ((mat == 0) ? ewq : (mat == 1) ? ewk : ewv) + (size_t)e * 589824;
    dst = wtexp + (size_t)(mat * 2 + e) * 589824;
  }
  int k0 = blockIdx.x * 32, n0 = blockIdx.y * 32;
  int tid = threadIdx.x;
#pragma unroll
  for (int i = 0; i < 4; ++i) {
    int lin = tid + 256 * i; int kk = lin >> 5, nn = lin & 31;
    t[kk][nn] = src[(size_t)(k0 + kk) * 768 + n0 + nn];
  }
  __syncthreads();
#pragma unroll
  for (int i = 0; i < 4; ++i) {
    int lin = tid + 256 * i; int nn = lin >> 5, kk = lin & 31;
    dst[(size_t)(n0 + nn) * 768 + k0 + kk] = f2bf(t[kk][nn]);
  }
}

// ---------- P3a: convert A (LoRA down) fp32 -> bf16, layout [768][128] ----------
__global__ __launch_bounds__(256) void k_acvt(const float* __restrict__ eaq, const float* __restrict__ eak,
                                              const float* __restrict__ eav,
                                              unsigned short* __restrict__ abt) {
  int z = blockIdx.z;  // mat*2+e
  int mat = z >> 1, e = z & 1;
  const float* src = ((mat == 0) ? eaq : (mat == 1) ? eak : eav) + (size_t)e * 98304;
  unsigned short* dst = abt + (size_t)z * 98304;
  int i = blockIdx.x * 256 + threadIdx.x;
  const float* p = src + (size_t)i * 8;
  float4 a = *(const float4*)p;
  float4 b = *(const float4*)(p + 4);
  u16x8 o;
  o[0] = f2bf(a.x); o[1] = f2bf(a.y); o[2] = f2bf(a.z); o[3] = f2bf(a.w);
  o[4] = f2bf(b.x); o[5] = f2bf(b.y); o[6] = f2bf(b.z); o[7] = f2bf(b.w);
  *(u16x8*)(dst + (size_t)i * 8) = o;
}

// ---------- P3b: transpose G [128][768] -> G^T bf16 [768][128] ----------
__global__ __launch_bounds__(256) void k_gtr(const float* __restrict__ egq, const float* __restrict__ egk,
                                             const float* __restrict__ egv,
                                             unsigned short* __restrict__ gtb) {
  __shared__ float t[32][33];
  int z = blockIdx.z;  // mat*2+e
  int mat = z >> 1, e = z & 1;
  const float* src = ((mat == 0) ? egq : (mat == 1) ? egk : egv) + (size_t)e * 98304;
  unsigned short* dst = gtb + (size_t)z * 98304;
  int n0 = blockIdx.x * 32, r0 = blockIdx.y * 32;
  int tid = threadIdx.x;
#pragma unroll
  for (int i = 0; i < 4; ++i) {
    int lin = tid + 256 * i; int rr = lin >> 5, nn = lin & 31;
    t[rr][nn] = src[(size_t)(r0 + rr) * 768 + n0 + nn];
  }
  __syncthreads();
#pragma unroll
  for (int i = 0; i < 4; ++i) {
    int lin = tid + 256 * i; int nn = lin >> 5, rr = lin & 31;
    dst[(size_t)(n0 + nn) * 128 + r0 + rr] = f2bf(t[rr][nn]);
  }
}

// ---------- P4: merged expert weight via MFMA: wte = W^T + G^T @ A^B  ----------
__global__ __launch_bounds__(256) void k_mergemm(const unsigned short* __restrict__ gtb,
                                                 const unsigned short* __restrict__ abt,
                                                 const unsigned short* __restrict__ wtexp,
                                                 unsigned short* __restrict__ wte) {
  const int z = blockIdx.z;  // mat*2+e
  const int m0 = blockIdx.x * 128, n0 = blockIdx.y * 128;
  const unsigned short* Am = gtb + (size_t)z * 98304;
  const unsigned short* Bm = abt + (size_t)z * 98304;
  const unsigned short* Wt = wtexp + (size_t)z * 589824;
  unsigned short* dst = wte + (size_t)z * 589824;
  __shared__ __align__(16) unsigned short As[128 * 32];
  __shared__ __align__(16) unsigned short Bs[128 * 32];
  const int tid = threadIdx.x, w = tid >> 6, lane = tid & 63, g = lane >> 4, l15 = lane & 15;
  const int wr = (w >> 1) * 64, wc = (w & 1) * 64;
  f32x4 acc[4][4] = {};
  for (int k0 = 0; k0 < 128; k0 += 32) {
#pragma unroll
    for (int c = 0; c < 2; ++c) {
      int o = (w * 2 + c) * 1024 + lane * 16;
      int row = o >> 6, chunk = (o >> 4) & 3;
      gload_lds16(Am + (size_t)(m0 + row) * 128 + k0 + (chunk << 3),
                  (char*)As + (w * 2 + c) * 1024);
      gload_lds16(Bm + (size_t)(n0 + row) * 128 + k0 + (chunk << 3),
                  (char*)Bs + (w * 2 + c) * 1024);
    }
    __syncthreads();
    bf16x8 af[4], bfr[4];
#pragma unroll
    for (int mi = 0; mi < 4; ++mi) {
      int row = wr + mi * 16 + l15;
      af[mi] = *(const bf16x8*)((const char*)As + row * 64 + (g << 4));
    }
#pragma unroll
    for (int ni = 0; ni < 4; ++ni) {
      int row = wc + ni * 16 + l15;
      bfr[ni] = *(const bf16x8*)((const char*)Bs + row * 64 + (g << 4));
    }
#pragma unroll
    for (int mi = 0; mi < 4; ++mi)
#pragma unroll
      for (int ni = 0; ni < 4; ++ni)
        acc[mi][ni] = mfma16(af[mi], bfr[ni], acc[mi][ni]);
    __syncthreads();
  }
#pragma unroll
  for (int ni = 0; ni < 4; ++ni) {
    int col = n0 + wc + ni * 16 + l15;
#pragma unroll
    for (int mi = 0; mi < 4; ++mi) {
#pragma unroll
      for (int r = 0; r < 4; ++r) {
        int row = m0 + wr + mi * 16 + 4 * g + r;
        size_t idx = (size_t)row * 768 + col;
        dst[idx] = f2bf(acc[mi][ni][r] + bf2f(Wt[idx]));
      }
    }
  }
}

// ---------- shared 256x256 phase helper (r10/r11-verified) ----------
template <int MH, int KK, bool LOADB>
DEVINL void qphase(const unsigned short* As, const unsigned short* Bs,
                   bf16x8 (&bfr)[4], f32x4 (&acc)[8][4],
                   int wr, int wc, int g, int l15) {
  if (LOADB) {
#pragma unroll
    for (int nj = 0; nj < 4; ++nj) {
      int row = wc + nj * 16 + l15;
      bfr[nj] = *(const bf16x8*)((const char*)Bs + row * 128 + (((KK * 4 + g) ^ (row & 7)) << 4));
    }
  }
  bf16x8 af[4];
#pragma unroll
  for (int mi = 0; mi < 4; ++mi) {
    int row = wr + MH * 64 + mi * 16 + l15;
    af[mi] = *(const bf16x8*)((const char*)As + row * 128 + (((KK * 4 + g) ^ (row & 7)) << 4));
  }
  __builtin_amdgcn_s_setprio(1);
#pragma unroll
  for (int mi = 0; mi < 4; ++mi)
#pragma unroll
    for (int nj = 0; nj < 4; ++nj)
      acc[MH * 4 + mi][nj] = mfma16(af[mi], bfr[nj], acc[MH * 4 + mi][nj]);
  __builtin_amdgcn_s_setprio(0);
}

// ---------- G1: QKV GEMM 256x256, BK=64, phased; z = mat + 3*(expert-base) ----------
__global__ __launch_bounds__(512, 2) void k_gemm_qkv(
    const unsigned short* __restrict__ xb, const unsigned short* __restrict__ wtc,
    const unsigned short* __restrict__ wte,
    const float* __restrict__ cbq, const float* __restrict__ cbk, const float* __restrict__ cbv,
    const float* __restrict__ ebq, const float* __restrict__ ebk, const float* __restrict__ ebv,
    const int* __restrict__ route,
    unsigned short* __restrict__ qC, unsigned short* __restrict__ kC, unsigned short* __restrict__ vC,
    unsigned short* __restrict__ qE, unsigned short* __restrict__ kE, unsigned short* __restrict__ vE,
    int base_expert) {
  extern __shared__ __align__(16) unsigned short smem[];  // 131072 B
  const int m0 = blockIdx.x * 256, n0 = blockIdx.y * 256;
  const int mat = blockIdx.z % 3;
  const int expert = base_expert + blockIdx.z / 3;
  const int b = m0 >> 9;
  const unsigned short* wt;
  const float* bias;
  if (!expert) {
    wt = wtc + (size_t)mat * 589824;
    bias = (mat == 0) ? cbq : (mat == 1) ? cbk : cbv;
  } else {
    int e = route[b];
    wt = wte + (size_t)(mat * 2 + e) * 589824;
    bias = ((mat == 0) ? ebq : (mat == 1) ? ebk : ebv) + e * 768;
  }
  unsigned short* outq = expert ? qE : qC;
  unsigned short* outk = expert ? kE : kC;
  unsigned short* vt   = expert ? vE : vC;
  const int tid = threadIdx.x, w = tid >> 6, lane = tid & 63, g = lane >> 4, l15 = lane & 15;
  const int wr = (w >> 2) * 128, wc = (w & 3) * 64;
  const int srow = lane >> 3, sslot = lane & 7;
  f32x4 acc[8][4] = {};

  auto stage_half = [&](int buf, int t, int h) {
    const unsigned short* src = (h < 2) ? xb : wt;
    int rowbase = (h < 2) ? (m0 + h * 128) : (n0 + (h - 2) * 128);
    unsigned short* lb = smem + buf * 32768 + ((h < 2) ? (h * 8192) : (16384 + (h - 2) * 8192));
    int k0 = t * 64;
#pragma unroll
    for (int c = 0; c < 2; ++c) {
      int rl = (w * 2 + c) * 8 + srow;
      int gc = (sslot ^ (rl & 7)) << 3;
      gload_lds16(src + (size_t)(rowbase + rl) * 768 + k0 + gc,
                  (char*)lb + (w * 2 + c) * 1024);
    }
  };

#pragma unroll
  for (int h = 0; h < 4; ++h) stage_half(0, 0, h);
  int cur = 0;
  for (int t = 0; t < 12; ++t) {
    const int nxt = cur ^ 1;
    const int tn = (t + 1 < 12) ? (t + 1) : 0;
    const unsigned short* As = smem + cur * 32768;
    const unsigned short* Bs = smem + cur * 32768 + 16384;
    bf16x8 bfr[4];
    stage_half(nxt, tn, 0);
    stage_half(nxt, tn, 2);
    asm volatile("s_waitcnt vmcnt(4)" ::: "memory");
    asm volatile("s_barrier" ::: "memory");
    qphase<0, 0, true>(As, Bs, bfr, acc, wr, wc, g, l15);
    stage_half(nxt, tn, 1);
    stage_half(nxt, tn, 3);
    asm volatile("s_barrier" ::: "memory");
    qphase<1, 0, false>(As, Bs, bfr, acc, wr, wc, g, l15);
    asm volatile("s_barrier" ::: "memory");
    qphase<0, 1, true>(As, Bs, bfr, acc, wr, wc, g, l15);
    asm volatile("s_barrier" ::: "memory");
    qphase<1, 1, false>(As, Bs, bfr, acc, wr, wc, g, l15);
    asm volatile("s_barrier" ::: "memory");
    cur = nxt;
  }
  __syncthreads();

  if (mat != 2) {
    unsigned short* pw = smem + w * 8192;
#pragma unroll
    for (int nj = 0; nj < 4; ++nj) {
      float bv = bias[n0 + wc + nj * 16 + l15];
#pragma unroll
      for (int fr = 0; fr < 8; ++fr)
#pragma unroll
        for (int r = 0; r < 4; ++r) {
          int lr = fr * 16 + 4 * g + r;
          int lc = nj * 16 + l15;
          pw[lr * 64 + (((lc >> 3) ^ (lr & 7)) << 3) + (lc & 7)] =
              f2bf(acc[fr][nj][r] + bv);
        }
    }
    unsigned short* dst = (mat == 0) ? outq : outk;
#pragma unroll
    for (int i = 0; i < 16; ++i) {
      int ci = i * 64 + lane;
      int row = ci >> 3;
      int c8 = ci & 7;
      u16x8 v = *(const u16x8*)(pw + row * 64 + ((c8 ^ (row & 7)) << 3));
      *(u16x8*)(dst + (size_t)(m0 + wr + row) * 768 + n0 + wc + c8 * 8) = v;
    }
  } else {
    unsigned short* Ts2 = smem;  // [128 cols][264]
#pragma unroll
    for (int p = 0; p < 2; ++p) {
      if (((w & 3) >> 1) == p) {
#pragma unroll
        for (int nj = 0; nj < 4; ++nj) {
          int ccl = ((w & 3) & 1) * 64 + nj * 16 + l15;
          float bv = bias[n0 + p * 128 + ccl];
#pragma unroll
          for (int fr = 0; fr < 8; ++fr)
#pragma unroll
            for (int r = 0; r < 4; ++r) {
              int row = wr + fr * 16 + 4 * g + r;
              Ts2[ccl * 264 + row] = f2bf(acc[fr][nj][r] + bv);
            }
        }
      }
      __syncthreads();
#pragma unroll
      for (int i = 0; i < 8; ++i) {
        int ci = tid + 512 * i, cc = ci >> 5, j = ci & 31;
        u16x8 v = *(const u16x8*)(Ts2 + cc * 264 + j * 8);
        int colg = n0 + p * 128 + cc;
        int head = colg >> 6, dh = colg & 63;
        *(u16x8*)(vt + ((size_t)((b * 12 + head) * 64 + dh)) * 512 + (m0 & 511) + j * 8) = v;
      }
      __syncthreads();
    }
  }
}

// ---------- A1: flash attention, single-buffer (r12 skeleton), SHUFFLE P-repack ----------
// P never touches LDS: after softmax, pack p[16] -> pk[mb][hh] (2xbf16/dword), then
// redistribute across the four 16-lane groups with __shfl (src keeps l15=query,
// g_src = (2g+(j>>1))&3; register mb selected by TARGET g>>1 via cndmask).
// Desk-verified: target lane(g,l15) word j = keys 32ks+8g+2j,+2j+1 of query l15.
__global__ __launch_bounds__(512) void k_attn(
    const unsigned short* __restrict__ Q0, const unsigned short* __restrict__ K0,
    const unsigned short* __restrict__ V0, unsigned short* __restrict__ ctx0,
    const unsigned short* __restrict__ Q1, const unsigned short* __restrict__ K1,
    const unsigned short* __restrict__ V1, unsigned short* __restrict__ ctx1,
    const float* __restrict__ mask) {
  const int qh = blockIdx.x, h = blockIdx.y;
  const int b = blockIdx.z & 31, path = blockIdx.z >> 5;
  const unsigned short* Q = path ? Q1 : Q0;
  const unsigned short* K = path ? K1 : K0;
  const unsigned short* Vt = path ? V1 : V0;
  unsigned short* ctx = path ? ctx1 : ctx0;
  const int tid = threadIdx.x, w = tid >> 6, lane = tid & 63, g = lane >> 4, l15 = lane & 15;
  const int qbase = b * 512 + qh * 256 + w * 32;
  bf16x8 qf[2][2];
#pragma unroll
  for (int qs = 0; qs < 2; ++qs) {
    const unsigned short* qp = Q + (size_t)(qbase + qs * 16 + l15) * 768 + h * 64;
    qf[qs][0] = *(const bf16x8*)(qp + g * 8);
    qf[qs][1] = *(const bf16x8*)(qp + 32 + g * 8);
  }
  __shared__ __align__(16) unsigned short Ks[64 * 64];
  __shared__ __align__(16) unsigned short Vs[64 * 64];
  __shared__ float mk2[512];
  float lsum[2] = {0.f, 0.f};
  f32x4 acc[2][4] = {};
  const unsigned short* Kb = K + (size_t)(b * 512) * 768 + h * 64;
  const unsigned short* Vb = Vt + (size_t)((b * 12 + h) * 64) * 512;
  const int srow = w * 8 + (lane >> 3);
  const int schunk = lane & 7;
  const int ssw = (schunk ^ (srow & 7)) << 3;
  const float C = 0.125f * 1.44269504f;
  // preload log2-domain mask bias once
  mk2[tid] = (1.f - mask[b * 512 + tid]) * (-14426.9504f);
  for (int kt = 0; kt < 8; ++kt) {
    const int kv0 = kt * 64;
    gload_lds16(Kb + (size_t)(kv0 + srow) * 768 + ssw, (char*)Ks + w * 1024);
    gload_lds16(Vb + (size_t)srow * 512 + kv0 + ssw, (char*)Vs + w * 1024);
    __syncthreads();
#pragma unroll
    for (int qs = 0; qs < 2; ++qs) {
      f32x4 sf[4];
#pragma unroll
      for (int mb = 0; mb < 4; ++mb) {
        int row = mb * 16 + l15;
        bf16x8 ka  = *(const bf16x8*)(Ks + row * 64 + ((g ^ (row & 7)) << 3));
        bf16x8 kb2 = *(const bf16x8*)(Ks + row * 64 + (((g + 4) ^ (row & 7)) << 3));
        f32x4 z = {0.f, 0.f, 0.f, 0.f};
        z = mfma16(ka, qf[qs][0], z);
        z = mfma16(kb2, qf[qs][1], z);
        sf[mb] = z;  // S^T[key=mb*16+4g+r][q=l15]
      }
      float p[16];
      float psum = 0.f;
#pragma unroll
      for (int mb = 0; mb < 4; ++mb)
#pragma unroll
        for (int r = 0; r < 4; ++r) {
          float e2 = exp2f(fmaf(sf[mb][r], C, mk2[kv0 + mb * 16 + g * 4 + r]));
          p[mb * 4 + r] = e2;
          psum += e2;
        }
      lsum[qs] += psum;
      // pack: pk[mb][hh] = bf16(p[mb*4+2hh]) | bf16(p[mb*4+2hh+1])<<16
      unsigned pk[4][2];
#pragma unroll
      for (int mb = 0; mb < 4; ++mb)
#pragma unroll
        for (int hh = 0; hh < 2; ++hh)
          pk[mb][hh] = (unsigned)f2bf(p[mb * 4 + 2 * hh]) |
                       ((unsigned)f2bf(p[mb * 4 + 2 * hh + 1]) << 16);
      // shuffle repack -> B-fragment, then PV
#pragma unroll
      for (int ks = 0; ks < 2; ++ks) {
        unsigned pb[4];
#pragma unroll
        for (int j = 0; j < 4; ++j) {
          int src = l15 + 16 * ((2 * g + (j >> 1)) & 3);
          unsigned t0 = __shfl(pk[2 * ks + 0][j & 1], src);
          unsigned t1 = __shfl(pk[2 * ks + 1][j & 1], src);
          pb[j] = (g >> 1) ? t1 : t0;
        }
        u32x4 pbv = {pb[0], pb[1], pb[2], pb[3]};
        bf16x8 pf = __builtin_bit_cast(bf16x8, pbv);
#pragma unroll
        for (int d = 0; d < 4; ++d) {
          int row = d * 16 + l15;
          bf16x8 vf = *(const bf16x8*)(Vs + row * 64 + (((g + 4 * ks) ^ (row & 7)) << 3));
          acc[qs][d] = mfma16(vf, pf, acc[qs][d]);
        }
      }
    }
    __syncthreads();
  }
#pragma unroll
  for (int qs = 0; qs < 2; ++qs) {
    float t = lsum[qs];
    t += __shfl_xor(t, 16);
    t += __shfl_xor(t, 32);
    float inv = 1.f / t;
    unsigned short* op = ctx + (size_t)(qbase + qs * 16 + l15) * 768 + h * 64;
#pragma unroll
    for (int d = 0; d < 4; ++d) {
      u16x4 o4;
#pragma unroll
      for (int r = 0; r < 4; ++r) o4[r] = f2bf(acc[qs][d][r] * inv);
      *(u16x4*)(op + d * 16 + 4 * g) = o4;
    }
  }
}

// ---------- G2: fused out-proj, 256x256 tile, K=1536 dual-source, phased ----------
__global__ __launch_bounds__(512, 2) void k_gemm_out(
    const unsigned short* __restrict__ ctxc, const unsigned short* __restrict__ ctxe,
    const unsigned short* __restrict__ woc, const unsigned short* __restrict__ woe,
    const float* __restrict__ cbo, const float* __restrict__ ebo,
    const int* __restrict__ route, float* __restrict__ out) {
  extern __shared__ __align__(16) unsigned short smem[];  // 131072 B
  const int m0 = blockIdx.x * 256, n0 = blockIdx.y * 256;
  const int b = m0 >> 9;
  const int e = route[b];
  const int tid = threadIdx.x, w = tid >> 6, lane = tid & 63, g = lane >> 4, l15 = lane & 15;
  const int wr = (w >> 2) * 128, wc = (w & 3) * 64;
  const int srow = lane >> 3, sslot = lane & 7;
  f32x4 acc[8][4] = {};

  auto stage_half = [&](int buf, int t, int h) {
    const unsigned short* src =
        (h < 2) ? ((t < 12) ? ctxc : ctxe)
                : ((t < 12) ? woc : (woe + (size_t)e * 589824));
    int rowbase = (h < 2) ? (m0 + h * 128) : (n0 + (h - 2) * 128);
    unsigned short* lb = smem + buf * 32768 + ((h < 2) ? (h * 8192) : (16384 + (h - 2) * 8192));
    int k0 = (t % 12) * 64;
#pragma unroll
    for (int c = 0; c < 2; ++c) {
      int rl = (w * 2 + c) * 8 + srow;
      int gc = (sslot ^ (rl & 7)) << 3;
      gload_lds16(src + (size_t)(rowbase + rl) * 768 + k0 + gc,
                  (char*)lb + (w * 2 + c) * 1024);
    }
  };

#pragma unroll
  for (int h = 0; h < 4; ++h) stage_half(0, 0, h);
  int cur = 0;
  for (int t = 0; t < 24; ++t) {
    const int nxt = cur ^ 1;
    const int tn = (t + 1 < 24) ? (t + 1) : 0;
    const unsigned short* As = smem + cur * 32768;
    const unsigned short* Bs = smem + cur * 32768 + 16384;
    bf16x8 bfr[4];
    stage_half(nxt, tn, 0);
    stage_half(nxt, tn, 2);
    asm volatile("s_waitcnt vmcnt(4)" ::: "memory");
    asm volatile("s_barrier" ::: "memory");
    qphase<0, 0, true>(As, Bs, bfr, acc, wr, wc, g, l15);
    stage_half(nxt, tn, 1);
    stage_half(nxt, tn, 3);
    asm volatile("s_barrier" ::: "memory");
    qphase<1, 0, false>(As, Bs, bfr, acc, wr, wc, g, l15);
    asm volatile("s_barrier" ::: "memory");
    qphase<0, 1, true>(As, Bs, bfr, acc, wr, wc, g, l15);
    asm volatile("s_barrier" ::: "memory");
    qphase<1, 1, false>(As, Bs, bfr, acc, wr, wc, g, l15);
    asm volatile("s_barrier" ::: "memory");
    cur = nxt;
  }
  __syncthreads();

  float* fs = (float*)smem;
#pragma unroll
  for (int p = 0; p < 4; ++p) {
    if ((w >> 2) == (p >> 1)) {
#pragma unroll
      for (int nj = 0; nj < 4; ++nj) {
        int lc = wc + nj * 16 + l15;
        int col = n0 + lc;
        float bsum = cbo[col] + ebo[e * 768 + col];
#pragma unroll
        for (int fi = 0; fi < 4; ++fi) {
          int fr = (p & 1) * 4 + fi;
#pragma unroll
          for (int r = 0; r < 4; ++r) {
            int lr = fi * 16 + 4 * g + r;
            fs[lr * 256 + (((lc >> 2) ^ (lr & 7)) << 2) + (lc & 3)] =
                acc[fr][nj][r] + bsum;
          }
        }
      }
    }
    __syncthreads();
#pragma unroll
    for (int j = 0; j < 8; ++j) {
      int ci = j * 512 + tid;
      int row = ci >> 6, sl = ci & 63;
      f32x4 v = *(const f32x4*)(fs + row * 256 + ((sl ^ (row & 7)) << 2));
      *(f32x4*)(out + (size_t)(m0 + p * 64 + row) * 768 + n0 + sl * 4) = v;
    }
    __syncthreads();
  }
}

extern "C" void kernel_launch(void* const* d_in, const int* in_sizes, int n_in,
                              void* d_out, int out_size, void* d_ws, size_t ws_size,
                              hipStream_t stream) {
  const float* x    = (const float*)d_in[0];
  const float* sw   = (const float*)d_in[1];
  const float* sb   = (const float*)d_in[2];
  const float* cwq  = (const float*)d_in[3];
  const float* cbq  = (const float*)d_in[4];
  const float* cwk  = (const float*)d_in[5];
  const float* cbk  = (const float*)d_in[6];
  const float* cwv  = (const float*)d_in[7];
  const float* cbv  = (const float*)d_in[8];
  const float* cwo  = (const float*)d_in[9];
  const float* cbo  = (const float*)d_in[10];
  const float* ewq  = (const float*)d_in[11];
  const float* ebq  = (const float*)d_in[12];
  const float* eaq  = (const float*)d_in[13];
  const float* egq  = (const float*)d_in[14];
  const float* ewk  = (const float*)d_in[15];
  const float* ebk  = (const float*)d_in[16];
  const float* eak  = (const float*)d_in[17];
  const float* egk  = (const float*)d_in[18];
  const float* ewv  = (const float*)d_in[19];
  const float* ebv  = (const float*)d_in[20];
  const float* eav  = (const float*)d_in[21];
  const float* egv  = (const float*)d_in[22];
  const float* ewo  = (const float*)d_in[23];
  const float* ebo  = (const float*)d_in[24];
  const float* amask = (const float*)d_in[25];
  (void)in_sizes; (void)n_in; (void)out_size;

  (void)hipFuncSetAttribute(reinterpret_cast<const void*>(k_gemm_qkv),
                            hipFuncAttributeMaxDynamicSharedMemorySize, 131072);
  (void)hipFuncSetAttribute(reinterpret_cast<const void*>(k_gemm_out),
                            hipFuncAttributeMaxDynamicSharedMemorySize, 131072);

  char* ws = (char*)d_ws;
  const size_t SZ = 25165824;  // 16384*768*2 bytes
  const size_t MERGED_NEED = 8 * SZ + 4718592 + 7077888 + 2359296 + 393216 + 256;
  const bool merged = (ws_size >= MERGED_NEED);

  unsigned short *xb, *qbC, *kC, *vC, *qbE, *kE, *vE, *ctxc, *ctxe;
  char* wbase;
  if (merged) {
    xb   = (unsigned short*)(ws);
    qbC  = (unsigned short*)(ws + SZ);
    kC   = (unsigned short*)(ws + 2 * SZ);
    vC   = (unsigned short*)(ws + 3 * SZ);
    qbE  = (unsigned short*)(ws + 4 * SZ);
    kE   = (unsigned short*)(ws + 5 * SZ);
    vE   = (unsigned short*)(ws + 6 * SZ);
    ctxc = (unsigned short*)(ws + 7 * SZ);
    ctxe = (unsigned short*)(ws);  // alias of xb (dead after merged qkv)
    wbase = ws + 8 * SZ;
  } else {
    xb   = (unsigned short*)(ws);
    qbC  = qbE = (unsigned short*)(ws + SZ);
    kC   = kE  = (unsigned short*)(ws + 2 * SZ);
    vC   = vE  = (unsigned short*)(ws + 3 * SZ);
    ctxc = (unsigned short*)(ws + 4 * SZ);
    ctxe = (unsigned short*)(ws);  // alias of xb
    wbase = ws + 5 * SZ;
  }
  unsigned short* wtc   = (unsigned short*)(wbase);
  unsigned short* wte   = (unsigned short*)(wbase + 4718592);
  unsigned short* wtewo = (unsigned short*)(wbase + 4718592 + 7077888);
  float* xsum           = (float*)(wbase + 4718592 + 7077888 + 2359296);
  int* route            = (int*)(wbase + 4718592 + 7077888 + 2359296 + 393216);
  unsigned short* abt   = (unsigned short*)(ws + SZ);
  unsigned short* gtb   = (unsigned short*)(ws + SZ + 1179648);
  unsigned short* wtexp = (unsigned short*)(ws + SZ + 2359296);

  k_cvt<<<6144, 256, 0, stream>>>(x, (u16x8*)xb);
  k_xsum<<<dim3(32, 3, 4), 256, 0, stream>>>(x, xsum);
  k_route<<<32, 256, 0, stream>>>(xsum, sw, sb, route);
  k_wt<<<dim3(24, 24, 12), 256, 0, stream>>>(cwq, cwk, cwv, cwo, ewo, ewq, ewk, ewv,
                                             wtc, wtewo, wtexp);
  k_acvt<<<dim3(48, 1, 6), 256, 0, stream>>>(eaq, eak, eav, abt);
  k_gtr<<<dim3(24, 4, 6), 256, 0, stream>>>(egq, egk, egv, gtb);
  k_mergemm<<<dim3(6, 6, 6), 256, 0, stream>>>(gtb, abt, wtexp, wte);

  if (merged) {
    k_gemm_qkv<<<dim3(64, 3, 6), 512, 131072, stream>>>(
        xb, wtc, wte, cbq, cbk, cbv, ebq, ebk, ebv, route,
        qbC, kC, vC, qbE, kE, vE, 0);
    k_attn<<<dim3(2, 12, 64), 512, 0, stream>>>(qbC, kC, vC, ctxc,
                                                qbE, kE, vE, ctxe, amask);
  } else {
    k_gemm_qkv<<<dim3(64, 3, 3), 512, 131072, stream>>>(
        xb, wtc, wte, cbq, cbk, cbv, ebq, ebk, ebv, route,
        qbC, kC, vC, qbC, kC, vC, 0);
    k_attn<<<dim3(2, 12, 32), 512, 0, stream>>>(qbC, kC, vC, ctxc,
                                                qbC, kC, vC, ctxc, amask);
    k_gemm_qkv<<<dim3(64, 3, 3), 512, 131072, stream>>>(
        xb, wtc, wte, cbq, cbk, cbv, ebq, ebk, ebv, route,
        qbC, kC, vC, qbC, kC, vC, 1);
    k_attn<<<dim3(2, 12, 32), 512, 0, stream>>>(qbC, kC, vC, ctxe,
                                                qbC, kC, vC, ctxe, amask);
  }
  k_gemm_out<<<dim3(64, 3), 512, 131072, stream>>>(ctxc, ctxe, wtc + 3 * 589824, wtewo,
                                                   cbo, ebo, route, (float*)d_out);
}